// Round 14
// baseline (345.426 us; speedup 1.0000x reference)
//
#include <hip/hip_runtime.h>
#include <stdint.h>

// ---------------------------------------------------------------------------
// MLP_42872363549033: ViT-B quantized MLP, exact-i8 formulation.
//   h   = gelu( quant(x,ka1) @ quant(W1,kw1)^T + b1 )
//   out = quant(h,ka2) @ quant(W2,kw2)^T + b2
// quant(x,K) = int8 * (K/127) exactly -> i8 MFMA with i32 accumulation.
//
// Round 12 kernel (3rd submission; rounds 12-13 hit GPU acquisition
// timeout): i8 port of the 256^2 8-phase template (m201 structure).
// 256x256 tile, BK=128B, 8 waves (2Mx4N), 128KB LDS double-buffer.
// Per phase: ds_read subtile || stage half-tile -> barrier -> setprio ->
// 16 MFMA -> barrier. Gates (vmcnt(0)+bar) at phases 4/8 only — exact by
// construction (stage windows: ph0-3 stage odd tile into buf1, ph4-7 stage
// next even tile into buf0). LDS swizzle slot = chunk ^ (row&7), applied
// pre-swizzled-source + swizzled-read (both-sides). B-frags cached across
// mh-phase pairs (24 ds_read/lane/K-tile vs 32).
// ---------------------------------------------------------------------------

typedef __attribute__((ext_vector_type(4))) int i32x4;

static constexpr int MROWS = 12608;   // 64 * 197
static constexpr int MPAD  = 12672;   // 99 * 128 (ws layout identical to r9)
static constexpr int DDIM  = 768;
static constexpr int HDIM  = 3072;

__device__ __forceinline__ int quant_one(float x, float K) {
    float xc = x / K;
    xc = fminf(fmaxf(xc, -1.0f), 1.0f);
    return (int)rintf(xc * 127.0f);   // v_rndne round-half-even = jnp.round
}

// ---- fused quantize: hidden | W1 | W2 in one launch -----------------------
__global__ void quant_fused_kernel(const float* __restrict__ x,
                                   const float* __restrict__ w1,
                                   const float* __restrict__ w2,
                                   int8_t* __restrict__ a8,
                                   int8_t* __restrict__ w1q,
                                   int8_t* __restrict__ w2q,
                                   const float* __restrict__ ka1,
                                   const float* __restrict__ kw1,
                                   const float* __restrict__ kw2) {
    constexpr int G1 = MPAD * DDIM / 4;
    constexpr int GV = MROWS * DDIM / 4;
    constexpr int G2 = HDIM * DDIM / 4;
    int i = blockIdx.x * 256 + threadIdx.x;
    const float4* src; int* dst; float K; int idx; bool valid = true;
    if (i < G1) {
        idx = i;           src = (const float4*)x;  dst = (int*)a8;  K = ka1[0];
        valid = i < GV;                      // pad rows -> 0
    } else if (i < G1 + G2) {
        idx = i - G1;      src = (const float4*)w1; dst = (int*)w1q; K = kw1[0];
    } else if (i < G1 + 2 * G2) {
        idx = i - G1 - G2; src = (const float4*)w2; dst = (int*)w2q; K = kw2[0];
    } else return;
    int packed = 0;
    if (valid) {
        float4 v = src[idx];
        packed = (quant_one(v.x, K) & 255)
               | ((quant_one(v.y, K) & 255) << 8)
               | ((quant_one(v.z, K) & 255) << 16)
               | ((quant_one(v.w, K) & 255) << 24);
    }
    dst[idx] = packed;
}

// ---- async global -> LDS, 16B per lane ------------------------------------
__device__ __forceinline__ void load16_to_lds(const int8_t* g, const int8_t* l) {
    __builtin_amdgcn_global_load_lds(
        (const __attribute__((address_space(1))) void*)g,
        (__attribute__((address_space(3))) void*)l, 16, 0, 0);
}

#define BAR()    asm volatile("s_barrier" ::: "memory")
#define VMCNT0() asm volatile("s_waitcnt vmcnt(0)" ::: "memory")

// ---- i8 GEMM, 256x256 tile, BK=128B, 8 waves (2Mx4N), 8-phase pipeline ----
// A: [MPAD][KD] K-major, B: [ND][KD] K-major. C[m,n] = sum_k A[m,k]*B[n,k].
// LDS: A/B tiles 256 rows x 128B, row r slot s holds global chunk s^(r&7).
template<int KD, int ND, bool EPI1>
__global__ __launch_bounds__(512, 2)
void gemm_i8_256(const int8_t* __restrict__ A, const int8_t* __restrict__ B,
                 int8_t* __restrict__ qout, float* __restrict__ fout,
                 const float* __restrict__ bias,
                 const float* __restrict__ kA, const float* __restrict__ kW,
                 const float* __restrict__ kQ) {
    __shared__ __align__(16) int8_t Ab0[32768];
    __shared__ __align__(16) int8_t Bb0[32768];
    __shared__ __align__(16) int8_t Ab1[32768];
    __shared__ __align__(16) int8_t Bb1[32768];

    const int tid  = threadIdx.x;
    const int lane = tid & 63;
    const int wave = tid >> 6;          // 0..7
    const int wr   = wave >> 2;         // 0..1  (M split)
    const int wc   = wave & 3;          // 0..3  (N split)

    // ---- bijective XCD-chunked block swizzle (m204 form) ----
    constexpr int NXB = ND / 256;
    const int nwg = gridDim.x;
    const int q   = nwg >> 3, r = nwg & 7;
    const int xcd = blockIdx.x & 7, loc = blockIdx.x >> 3;
    const int nb  = (xcd < r ? xcd * (q + 1) : r * (q + 1) + (xcd - r) * q) + loc;
    const int bm  = min((nb / NXB) * 256, MPAD - 256);   // clamped overlap tile
    const int bn  = (nb % NXB) * 256;

    i32x4 acc[8][4] = {};
    i32x4 bf_[4];   // B fragments, cached across mh-phase pairs

    // ---- staging source (pre-swizzled): thread covers row tid>>3 (+64/instr2)
    //      global chunk = (tid&7) ^ ((tid>>3)&7); LDS dest linear 16*tid.
    const int soff = (((tid & 7) ^ ((tid >> 3) & 7)) << 4);
    const int8_t* gA = A + (size_t)(bm + (tid >> 3)) * KD + soff;
    const int8_t* gB = B + (size_t)(bn + (tid >> 3)) * KD + soff;

    // STG: stage half H (128 rows) of a tile at K-byte KB into LDS buffer LB.
#define STG(GP, LB, KB, H)                                                     \
    do {                                                                       \
        load16_to_lds(GP + (size_t)((H) * 128) * KD + (KB),                    \
                      LB + (H) * 16384 + 16 * tid);                            \
        load16_to_lds(GP + (size_t)((H) * 128 + 64) * KD + (KB),               \
                      LB + (H) * 16384 + 8192 + 16 * tid);                     \
    } while (0)

    // ---- fragment read addressing (swizzled): ks=1 flips byte bit6 ----
    const int fr  = lane & 15;
    const int q4  = lane >> 4;
    const int sl0 = ((q4 ^ (fr & 7)) << 4);
    int aoff[8], boff[4];
#pragma unroll
    for (int m = 0; m < 8; ++m) aoff[m] = (wr * 128 + m * 16 + fr) * 128 + sl0;
#pragma unroll
    for (int n = 0; n < 4; ++n) boff[n] = (wc * 64 + n * 16 + fr) * 128 + sl0;

    // PHASE: ds_read (B if READB, A quad MH at KS) || stage stmt -> bar ->
    //        setprio(1) -> 16 MFMA -> setprio(0) -> bar.
#define PHASE(MH, KS, ABUF, BBUF, READB, ...)                                  \
    do {                                                                       \
        i32x4 af_[4];                                                          \
        if (READB) {                                                           \
            _Pragma("unroll")                                                  \
            for (int n = 0; n < 4; ++n)                                        \
                bf_[n] = *reinterpret_cast<const i32x4*>(                      \
                    BBUF + (boff[n] ^ ((KS) * 64)));                           \
        }                                                                      \
        _Pragma("unroll")                                                      \
        for (int m = 0; m < 4; ++m)                                            \
            af_[m] = *reinterpret_cast<const i32x4*>(                          \
                ABUF + (aoff[(MH) * 4 + m] ^ ((KS) * 64)));                    \
        __VA_ARGS__;                                                           \
        BAR();                                                                 \
        __builtin_amdgcn_s_setprio(1);                                         \
        _Pragma("unroll")                                                      \
        for (int m = 0; m < 4; ++m)                                            \
            _Pragma("unroll")                                                  \
            for (int n = 0; n < 4; ++n)                                        \
                acc[(MH) * 4 + m][n] = __builtin_amdgcn_mfma_i32_16x16x64_i8(  \
                    af_[m], bf_[n], acc[(MH) * 4 + m][n], 0, 0, 0);            \
        __builtin_amdgcn_s_setprio(0);                                         \
        BAR();                                                                 \
    } while (0)

    constexpr int NIT = KD / 256;   // 3 (GEMM1) / 12 (GEMM2)

    // ---- prologue: stage tile 0 (4 halves) into buf0, drain, sync ----
    STG(gA, Ab0, 0, 0); STG(gA, Ab0, 0, 1);
    STG(gB, Bb0, 0, 0); STG(gB, Bb0, 0, 1);
    VMCNT0(); BAR();

    for (int j = 0; j < NIT; ++j) {
        const int kb1 = j * 256 + 128;       // odd tile K-offset
        const int kb2 = j * 256 + 256;       // next even tile K-offset
        const bool more = (j + 1 < NIT);
        // phases 0-3: compute buf0 (tile 2j), stage tile 2j+1 into buf1
        PHASE(0, 0, Ab0, Bb0, true,  STG(gA, Ab1, kb1, 0));
        PHASE(1, 0, Ab0, Bb0, false, STG(gA, Ab1, kb1, 1));
        PHASE(0, 1, Ab0, Bb0, true,  STG(gB, Bb1, kb1, 0));
        PHASE(1, 1, Ab0, Bb0, false, STG(gB, Bb1, kb1, 1));
        VMCNT0(); BAR();                     // buf1 resident (gate 1)
        // phases 4-7: compute buf1 (tile 2j+1), stage tile 2j+2 into buf0
        PHASE(0, 0, Ab1, Bb1, true,  if (more) STG(gA, Ab0, kb2, 0));
        PHASE(1, 0, Ab1, Bb1, false, if (more) STG(gA, Ab0, kb2, 1));
        PHASE(0, 1, Ab1, Bb1, true,  if (more) STG(gB, Bb0, kb2, 0));
        PHASE(1, 1, Ab1, Bb1, false, if (more) STG(gB, Bb0, kb2, 1));
        VMCNT0(); BAR();                     // buf0 resident for next iter (gate 2)
    }
#undef PHASE
#undef STG

    // ---- epilogue ----
    const float sAW = kA[0] * kW[0] * (1.0f / 16129.0f);   // (kA/127)*(kW/127)
    float kq = 1.0f;
    if constexpr (EPI1) kq = kQ[0];

    const int row0 = bm + wr * 128 + (q4 << 2);
    const int col0 = bn + wc * 64 + fr;
#pragma unroll
    for (int m = 0; m < 8; ++m) {
#pragma unroll
        for (int n = 0; n < 4; ++n) {
            const int col = col0 + n * 16;
            const float bv = bias[col];
#pragma unroll
            for (int jj = 0; jj < 4; ++jj) {
                const int row = row0 + m * 16 + jj;
                float h = (float)acc[m][n][jj] * sAW + bv;
                if constexpr (EPI1) {
                    float g  = 0.5f * h * (1.0f + erff(h * 0.70710678118654752f));
                    float xc = fminf(fmaxf(g / kq, -1.0f), 1.0f);
                    qout[(size_t)row * ND + col] = (int8_t)(int)rintf(xc * 127.0f);
                } else {
                    if (row < MROWS)
                        fout[(size_t)row * ND + col] = h;
                }
            }
        }
    }
}

// ---------------------------------------------------------------------------
extern "C" void kernel_launch(void* const* d_in, const int* in_sizes, int n_in,
                              void* d_out, int out_size, void* d_ws, size_t ws_size,
                              hipStream_t stream) {
    const float* hidden = (const float*)d_in[0];
    const float* W1     = (const float*)d_in[1];
    const float* b1     = (const float*)d_in[2];
    const float* W2     = (const float*)d_in[3];
    const float* b2     = (const float*)d_in[4];
    const float* ka1    = (const float*)d_in[5];
    const float* kw1    = (const float*)d_in[6];
    const float* ka2    = (const float*)d_in[7];
    const float* kw2    = (const float*)d_in[8];
    float* out = (float*)d_out;

    int8_t* a8  = (int8_t*)d_ws;                    //  [MPAD][DDIM]
    int8_t* w1q = a8  + (size_t)MPAD * DDIM;        //  [HDIM][DDIM]
    int8_t* w2q = w1q + (size_t)HDIM * DDIM;        //  [DDIM][HDIM]
    int8_t* h8  = w2q + (size_t)DDIM * HDIM;        //  [MPAD][HDIM]

    {
        constexpr int GTOT = (MPAD * DDIM + 2 * HDIM * DDIM) / 4;
        quant_fused_kernel<<<(GTOT + 255) / 256, 256, 0, stream>>>(
            hidden, W1, W2, a8, w1q, w2q, ka1, kw1, kw2);
    }

    // GEMM1: M blocks = 50 (clamped overlap), N blocks = 12 -> 600 blocks
    gemm_i8_256<DDIM, HDIM, true>
        <<<((MPAD + 255) / 256) * (HDIM / 256), 512, 0, stream>>>
        (a8, w1q, h8, nullptr, b1, ka1, kw1, ka2);

    // GEMM2: 50 x 3 = 150 blocks
    gemm_i8_256<HDIM, DDIM, false>
        <<<((MPAD + 255) / 256) * (DDIM / 256), 512, 0, stream>>>
        (h8, w2q, nullptr, out, b2, ka2, kw2, nullptr);
}